// Round 13
// baseline (2094.630 us; speedup 1.0000x reference)
//
#include <hip/hip_runtime.h>
#include <hip/hip_bf16.h>
#include <hip/hip_fp16.h>

// LSTM_RNN: B=128, T=512, E=256, U=512. R27 = R26 RESUBMITTED (R26 bench
// died to infra: "MI355X container failed twice" — same fingerprint as
// R19, which resubmitted cleanly as R20. Kernel progress argument is
// R25's proven one: budget-4096 RMW polls + agent-shadow fallback; the
// per-wave gate only adds pollers at a contention level R24 already
// proved harmless).
//   R26/R27 = R25 + PER-WAVE INDEPENDENT GATE (deletes the wave0 -> LDS
//   'go' -> spin-wake relay).
//   R25 post-mortem: counter aggregation cut WRITE 12.3->8.8MB but timing
//   flat (1705->1735, node band +-2%) => contention immaterial; chain is
//   latency-intrinsic. Consolidated cache model (R16-R25): cross-CU
//   SIGNAL WRITES must be atomic RMWs (execute at L2 immediately); plain/
//   sc0 stores linger in the producer store buffer (R16 hang, R17/R18
//   budget exhaustion). Data stores are fine (vmcnt-drained before the
//   signal). Polls: RMW add-0 sc0 (R21-proven).
//   - Each kh0 wave gates ITSELF: lane0 RMW-polls the per-domain counter
//     (>= 16*ceil(t/2)), readfirstlane-broadcasts, wave immediately
//     issues its own bulk. Removes the observe->LDS->wake relay
//     (~200-400cy) and unpins bulk issue from the single poller.
//   - Publish R25-verbatim: per-wave vmcnt(0) drain -> LDS pcnt; 4th
//     arrival does counter+=1 (atomic add, L2) + agent shadow += 1
//     (hang guard).
//   - Induction unchanged: counter>=target implies all step-(t-1)
//     publishes, each following that slice's step-(t-1) bulk reads
//     (program order) => visibility AND WAR as before.
//   Everything else R24/R25-verbatim: transposed MFMA (operand swap,
//   packed 8B h-stores), coalesced 8x512B sc0 bulk + LDS stage + B2,
//   Rs + B3, XCC probe gating the sc0 data path, memset-0 flags.
// ws layout (~33.82 MiB):
//   X      fp16 [T][B][E]        @ 0          (33,554,432 B)
//   Hq     fp16 [2][8][16][512]  @ 33,554,432 (262,144 B)
//   FlagA  u32  [2][8][16]       @ 33,816,576 (1,024 B) counter@idx*16 (L2)
//   FlagB  u32  [2][8][16]       @ 33,817,600 (1,024 B) shadow (agent/LLC)
//   XccTab u32  [128]            @ 33,818,624 (512 B)
//   (FlagA..XccTab = 2,560 B contiguous, memset 0 each launch)

#define B_ 128
#define T_ 512
#define E_ 256
#define U_ 512
#define NWG_ 128
#define HROW_ 516   // Hs row stride (halves)

typedef __attribute__((ext_vector_type(4))) _Float16 half4;
typedef __attribute__((ext_vector_type(4))) float floatx4;
typedef unsigned long long u64t;
typedef unsigned int u32t;

#define MFMA16 __builtin_amdgcn_mfma_f32_16x16x16f16

__device__ __forceinline__ float sigmf(float x) { return 1.0f / (1.0f + __expf(-x)); }
__device__ __forceinline__ float tanh_f(float x) { return 2.0f / (1.0f + __expf(-2.0f * x)) - 1.0f; }

// X[t][b][e] = (fp16) emb[sentence[b][t]][e]; one thread = 8 elements.
__global__ void prep_x_kernel(const int* __restrict__ sent,
                              const float* __restrict__ emb,
                              _Float16* __restrict__ X) {
  int gid = blockIdx.x * blockDim.x + threadIdx.x;  // 2,097,152 total
  int e8 = gid & 31;
  int row = gid >> 5;         // row = t*128 + b
  int b = row & 127;
  int t = row >> 7;
  int word = sent[b * T_ + t];
  const float* src = emb + (size_t)word * E_ + e8 * 8;
  float4 v0 = *(const float4*)(src);
  float4 v1 = *(const float4*)(src + 4);
  _Float16 o[8] = {(_Float16)v0.x, (_Float16)v0.y, (_Float16)v0.z, (_Float16)v0.w,
                   (_Float16)v1.x, (_Float16)v1.y, (_Float16)v1.z, (_Float16)v1.w};
  _Float16* dst = X + (size_t)row * E_ + e8 * 8;
  *(half4*)dst = *(half4*)o;
  *(half4*)(dst + 4) = *(half4*)(o + 4);
}

__global__ __launch_bounds__(512, 1) void lstm_kernel(
    const _Float16* __restrict__ X,
    const float* __restrict__ Wx, const float* __restrict__ Wh,
    const float* __restrict__ bias,
    _Float16* __restrict__ Hq, u32t* FlagA, u32t* FlagB, u32t* XccTab) {
  // LDS: Hs [16][HROW_] fp16 (16,512) | Rs float[4][512] (8,192) |
  // xl u32[128] (512) | pcnt u32 = 25,220 used; padded to 96 KB.
  __shared__ __align__(16) char smem[98304];
  _Float16* Hs = (_Float16*)smem;
  float* Rs = (float*)(smem + 16512);
  u32t* xl = (u32t*)(smem + 24704);
  u32t* pcntP = (u32t*)(smem + 25216);

  const int bid = blockIdx.x;
  const int d = bid & 7;    // domain: rows d*16 .. d*16+15 (one XCD, verified)
  const int s = bid >> 3;   // unit slice: units s*32 .. s*32+31
  const int tid = threadIdx.x;
  const int lane = tid & 63;
  const int wave = tid >> 6;      // 8 waves
  const int p16 = lane & 15;
  const int quad = lane >> 4;
  const int sg = wave & 3;        // unit subgroup (8 units)
  const int kh = wave >> 2;       // 0: exchange + h[0,256) + epilogue
                                  // 1: x-GEMM + h[256,512)

  // ---- one-time XCD-mapping probe (gates the L2-local DATA path) ----
  // hwreg(HW_REG_XCC_ID=20, offset=0, size=32) -> imm = (31<<11)|20 = 63508
  if (tid == 0) {
    *pcntP = 0u;
    u32t myx = (u32t)__builtin_amdgcn_s_getreg(63508) & 0xFFu;
    __hip_atomic_store(XccTab + bid, 0x5A5A0000u | myx, __ATOMIC_RELAXED,
                       __HIP_MEMORY_SCOPE_AGENT);
  }
  if (wave == 0) {
    u32t v0, v1;
    for (;;) {
      v0 = __hip_atomic_load(XccTab + lane, __ATOMIC_RELAXED,
                             __HIP_MEMORY_SCOPE_AGENT);
      v1 = __hip_atomic_load(XccTab + 64 + lane, __ATOMIC_RELAXED,
                             __HIP_MEMORY_SCOPE_AGENT);
      if (__all(((v0 >> 16) == 0x5A5Au) & ((v1 >> 16) == 0x5A5Au))) break;
      __builtin_amdgcn_s_sleep(8);
    }
    xl[lane] = v0;
    xl[lane + 64] = v1;
  }
  __syncthreads();
  int fastv;
  {
    const u32t ref = xl[d];
    bool dom = true;
    for (int j = 1; j < 16; ++j) dom = dom && (xl[d + 8 * j] == ref);
    bool sane = false;  // getreg sanity: a constant-reading getreg -> slow
    const u32t z0 = xl[0];
    for (int e = 1; e < 128; ++e) sane = sane || (xl[e] != z0);
    fastv = (dom && sane) ? 1 : 0;
  }
  const bool fastp = (bool)__builtin_amdgcn_readfirstlane(fastv);

  // ---- one-time: gather this wave's B-fragments into VGPRs ----
  // (With operands swapped, this data is the A'-fragment
  //  A'[m=lane&15][k=quad*4+j] = W[gk][C(m)].)
  const int C0 = ((p16 >> 3) & 1) * 512 + s * 32 + sg * 8 + (p16 & 7);  // i/f
  const int C1 = C0 + 1024;                                             // g/o
  half4 b0r[32], b1r[32];
  if (kh == 0) {
#pragma unroll
    for (int i = 0; i < 16; ++i) {
      int kb = 16 + i;
#pragma unroll
      for (int j = 0; j < 4; ++j) {
        int gk = kb * 16 + quad * 4 + j;
        b0r[i][j] = (_Float16)Wh[(size_t)(gk - E_) * 2048 + C0];
        b1r[i][j] = (_Float16)Wh[(size_t)(gk - E_) * 2048 + C1];
      }
    }
  } else {
#pragma unroll
    for (int i = 0; i < 32; ++i) {
      int kb = (i < 16) ? i : (16 + i);
#pragma unroll
      for (int j = 0; j < 4; ++j) {
        int gk = kb * 16 + quad * 4 + j;
        float w0 = (gk < E_) ? Wx[(size_t)gk * 2048 + C0]
                             : Wh[(size_t)(gk - E_) * 2048 + C0];
        float w1 = (gk < E_) ? Wx[(size_t)gk * 2048 + C1]
                             : Wh[(size_t)(gk - E_) * 2048 + C1];
        b0r[i][j] = (_Float16)w0;
        b1r[i][j] = (_Float16)w1;
      }
    }
  }

  // ---- transposed-epilogue constants (kh0) ----
  const int u0 = s * 32 + sg * 8 + (quad & 1) * 4;
  const floatx4 bi = *(const floatx4*)(bias + u0);          // i
  const floatx4 bf = *(const floatx4*)(bias + 512 + u0);    // f
  const floatx4 bg = *(const floatx4*)(bias + 1024 + u0);   // g
  const floatx4 bo = *(const floatx4*)(bias + 1536 + u0);   // o

  float cst[4] = {0.f, 0.f, 0.f, 0.f};  // c-state (kh0, quad<2 lanes)

  const int brow = d * 16 + p16;   // x/h fragment batch row
  const int ko = quad * 4;

  for (int t = 0; t < T_; ++t) {
    const int pin = t & 1, pout = pin ^ 1;

    floatx4 acc0 = {0.f, 0.f, 0.f, 0.f};
    floatx4 acc1 = {0.f, 0.f, 0.f, 0.f};

    if (kh == 1) {
      // ---- x-GEMM (kh1 only): 16 K16-blocks, operands swapped ----
      const _Float16* xr = X + ((size_t)t * B_ + brow) * E_ + ko;
#pragma unroll
      for (int i = 0; i < 16; ++i) {
        half4 a = *(const half4*)(xr + i * 16);
        acc0 = MFMA16(b0r[i], a, acc0, 0, 0, 0);
        acc1 = MFMA16(b1r[i], a, acc1, 0, 0, 0);
      }
    } else if (t > 0) {
      // ---- exchange (kh0 only): PER-WAVE gate + bulk + stage ----
      // cumulative counter target: publishes to parity t&1 come from steps
      // t-1, t-3, ... -> 16 * ceil(t/2).
      const u32t target = 16u * (((u32t)t + 1u) >> 1);
      u32t v = target;   // lanes != 0 carry a dummy; lane0 polls
      if (lane == 0) {
        if (fastp) {
          u32t* ap = FlagA + (size_t)(pin * 8 + d) * 16;
          const u32t* fb = FlagB + (size_t)(pin * 8 + d) * 16;
          int budget = 4096;   // RMW channel R21-proven; fallback = guard
          for (;;) {
            if (budget > 0) {
              asm volatile(
                  "global_atomic_add %0, %1, %2, off sc0\n\t"
                  "s_waitcnt vmcnt(0)"
                  : "=&v"(v) : "v"(ap), "v"(0u) : "memory");
            } else {
              v = __hip_atomic_load(fb, __ATOMIC_RELAXED,
                                    __HIP_MEMORY_SCOPE_AGENT);
              __builtin_amdgcn_s_sleep(1);
            }
            if (v >= target) break;
            --budget;
          }
        } else {
          const u32t* fb = FlagB + (size_t)(pin * 8 + d) * 16;
          for (;;) {
            v = __hip_atomic_load(fb, __ATOMIC_RELAXED,
                                  __HIP_MEMORY_SCOPE_AGENT);
            if (v >= target) break;
            __builtin_amdgcn_s_sleep(1);
          }
        }
      }
      // broadcast lane0's observed value; pins the bulk via dep.
      v = (u32t)__builtin_amdgcn_readfirstlane(v);
      const size_t dep = (size_t)(v >> 16);  // counter <= 4096 -> 0

      // bulk: 4 rows/wave (rows wave*4 .. wave*4+3), 8 chunks of 512B
      const _Float16* hq =
          Hq + ((size_t)(pin * 8 + d) * 16 + wave * 4) * 512 + dep;
      u64t hv[8];
      if (fastp) {
        // ONE asm block: 8 pipelined sc0 loads (imm offsets), one vmcnt(0).
        const u64t* hqb = (const u64t*)hq + lane;
        u64t h0, h1, h2, h3, h4, h5, h6, h7;
        asm volatile(
            "global_load_dwordx2 %0, %8, off sc0\n\t"
            "global_load_dwordx2 %1, %8, off offset:512 sc0\n\t"
            "global_load_dwordx2 %2, %8, off offset:1024 sc0\n\t"
            "global_load_dwordx2 %3, %8, off offset:1536 sc0\n\t"
            "global_load_dwordx2 %4, %8, off offset:2048 sc0\n\t"
            "global_load_dwordx2 %5, %8, off offset:2560 sc0\n\t"
            "global_load_dwordx2 %6, %8, off offset:3072 sc0\n\t"
            "global_load_dwordx2 %7, %8, off offset:3584 sc0\n\t"
            "s_waitcnt vmcnt(0)"
            : "=&v"(h0), "=&v"(h1), "=&v"(h2), "=&v"(h3),
              "=&v"(h4), "=&v"(h5), "=&v"(h6), "=&v"(h7)
            : "v"(hqb)
            : "memory");
        hv[0] = h0; hv[1] = h1; hv[2] = h2; hv[3] = h3;
        hv[4] = h4; hv[5] = h5; hv[6] = h6; hv[7] = h7;
      } else {
#pragma unroll
        for (int j = 0; j < 8; ++j) {
          size_t idx = (size_t)(j >> 1) * 128 + (j & 1) * 64 + lane;
          hv[j] = __hip_atomic_load((const u64t*)hq + idx, __ATOMIC_RELAXED,
                                    __HIP_MEMORY_SCOPE_AGENT);
        }
      }
#pragma unroll
      for (int j = 0; j < 8; ++j) {
        int r = wave * 4 + (j >> 1), half = j & 1;
        *(u64t*)(Hs + r * HROW_ + half * 256 + lane * 4) = hv[j];
      }
    }
    __syncthreads();  // B2: slab ready + x partial-accs in flight

    if (t > 0) {
      // ---- h-GEMM from slab (operands swapped; reads unchanged) ----
#pragma unroll
      for (int i = 0; i < 16; ++i) {
        int hk = kh * 16 + i;
        half4 a = *(const half4*)(Hs + p16 * HROW_ + hk * 16 + ko);
        const int wi = (kh == 0) ? i : (16 + i);
        acc0 = MFMA16(b0r[wi], a, acc0, 0, 0, 0);
        acc1 = MFMA16(b1r[wi], a, acc1, 0, 0, 0);
      }
    }

    // ---- kh1 partials -> Rs (same transposed layout both kh groups) ----
    if (kh == 1) {
      float* wb = Rs + sg * 512;
      *(floatx4*)(wb + lane * 4) = acc0;
      *(floatx4*)(wb + 256 + lane * 4) = acc1;
    }
    __syncthreads();  // B3: partials ready. kh1 then free-runs to t+1.

    // ---- epilogue (kh0): transposed — packed 8B h store per lane ----
    if (kh == 0) {
      const float* rb = Rs + sg * 512;
      floatx4 z0v = acc0 + *(const floatx4*)(rb + lane * 4);      // i | f
      floatx4 z1v = acc1 + *(const floatx4*)(rb + 256 + lane * 4); // g | o
      half4 hp4;
#pragma unroll
      for (int r = 0; r < 4; ++r) {
        float fraw = __shfl_xor(z0v[r], 32, 64);  // partner's f (quad<2 rx)
        float oraw = __shfl_xor(z1v[r], 32, 64);  // partner's o
        float iv = sigmf(z0v[r] + bi[r]);
        float gv = tanh_f(z1v[r] + bg[r]);
        float fv = sigmf(fraw + bf[r]);
        float ov = sigmf(oraw + bo[r]);
        float cn = fv * cst[r] + iv * gv;
        cst[r] = cn;
        hp4[r] = (_Float16)(ov * tanh_f(cn));
      }
      if (quad < 2) {
        // h for units u0..u0+3 of batch row p16: ONE contiguous 8B store.
        u64t pk = __builtin_bit_cast(u64t, hp4);
        u64t* hp =
            (u64t*)(Hq + ((size_t)(pout * 8 + d) * 16 + p16) * 512 + u0);
        if (fastp) {
          *hp = pk;  // plain: L1 write-through -> dirty in local XCD-L2
        } else {
          __hip_atomic_store(hp, pk, __ATOMIC_RELAXED,
                             __HIP_MEMORY_SCOPE_AGENT);
        }
      }

      // ---- publish: per-wave drain + LDS counter; counter += 1 ----
      asm volatile("s_waitcnt vmcnt(0)" ::: "memory");
      __builtin_amdgcn_sched_barrier(0);
      if (lane == 0) {
        u32t old = atomicAdd(pcntP, 1u);
        if (old == (u32t)(4 * t + 3)) {
          size_t fo = (size_t)(pout * 8 + d) * 16;
          if (fastp) {
            u32t* ap = FlagA + fo;
            asm volatile("global_atomic_add %0, %1, off"
                         :: "v"(ap), "v"(1u) : "memory");
          }
          __hip_atomic_fetch_add(FlagB + fo, 1u, __ATOMIC_RELAXED,
                                 __HIP_MEMORY_SCOPE_AGENT);  // shadow/guard
        }
      }
    }
  }
}

// MLP head: one block per batch row. h(512)->relu 128->relu 64->sigmoid 1.
// T=512 even -> final h in Hq parity 0. Kernel boundary orders prior stores
// (end-of-dispatch agent release writes back dirty L2 lines).
__global__ void head_kernel(const _Float16* __restrict__ Hq,
                            const float* __restrict__ W1, const float* __restrict__ b1,
                            const float* __restrict__ W2, const float* __restrict__ b2,
                            const float* __restrict__ W3, const float* __restrict__ b3,
                            float* __restrict__ out) {
  __shared__ float hs[512];
  __shared__ float h1[128];
  __shared__ float h2[64];
  int row = blockIdx.x;
  int tid = threadIdx.x;  // 128 threads
  int dd = row >> 4, rr = row & 15;
  const _Float16* hrow = Hq + ((size_t)dd * 16 + rr) * 512;
  for (int k = tid; k < 512; k += 128) hs[k] = (float)hrow[k];
  __syncthreads();
  float a = b1[tid];
  for (int k = 0; k < 512; ++k) a += hs[k] * W1[k * 128 + tid];
  h1[tid] = fmaxf(a, 0.0f);
  __syncthreads();
  if (tid < 64) {
    float a2 = b2[tid];
    for (int k = 0; k < 128; ++k) a2 += h1[k] * W2[k * 64 + tid];
    h2[tid] = fmaxf(a2, 0.0f);
  }
  __syncthreads();
  if (tid == 0) {
    float a3 = b3[0];
    for (int k = 0; k < 64; ++k) a3 += h2[k] * W3[k];
    out[row] = 1.0f / (1.0f + __expf(-a3));
  }
}

extern "C" void kernel_launch(void* const* d_in, const int* in_sizes, int n_in,
                              void* d_out, int out_size, void* d_ws, size_t ws_size,
                              hipStream_t stream) {
  const int* sent = (const int*)d_in[0];
  const float* emb = (const float*)d_in[1];
  const float* Wx = (const float*)d_in[2];
  const float* Wh = (const float*)d_in[3];
  const float* b = (const float*)d_in[4];
  const float* W1 = (const float*)d_in[5];
  const float* b1 = (const float*)d_in[6];
  const float* W2 = (const float*)d_in[7];
  const float* b2 = (const float*)d_in[8];
  const float* W3 = (const float*)d_in[9];
  const float* b3 = (const float*)d_in[10];
  float* out = (float*)d_out;

  char* ws = (char*)d_ws;
  _Float16* X = (_Float16*)(ws);
  _Float16* Hq = (_Float16*)(ws + (size_t)33554432);
  u32t* FlagA = (u32t*)(ws + (size_t)33554432 + 262144);
  u32t* FlagB = (u32t*)(ws + (size_t)33554432 + 263168);
  u32t* XccTab = (u32t*)(ws + (size_t)33554432 + 264192);

  // Zero FlagA+FlagB+XccTab (contiguous 2,560 B) every launch:
  // counters are cumulative from 0; 0 never satisfies a t>=1 target.
  hipMemsetAsync(FlagA, 0, 2560, stream);
  prep_x_kernel<<<8192, 256, 0, stream>>>(sent, emb, X);
  lstm_kernel<<<NWG_, 512, 0, stream>>>(X, Wx, Wh, b, Hq, FlagA, FlagB, XccTab);
  head_kernel<<<128, 128, 0, stream>>>(Hq, W1, b1, W2, b2, W3, b3, out);
}

// Round 14
// 1775.437 us; speedup vs baseline: 1.1798x; 1.1798x over previous
//
#include <hip/hip_runtime.h>
#include <hip/hip_bf16.h>
#include <hip/hip_fp16.h>

// LSTM_RNN: B=128, T=512, E=256, U=512. R28 = R24 VERBATIM REVERT (the
// session's measured-best configuration, 1705us steady).
//   Gate-structure search is complete and this is its optimum:
//   - R24 (1705): per-slice flags (16 words), wave0 16-lane RMW poll +
//     LDS go release. BEST.
//   - R25 (1735): aggregated 1-word counter, 16 pollers/word — flat.
//   - R27 (2010): per-wave gate, 64 pollers on ONE word — publisher RMW
//     queues behind the poll storm (WRITE 8.8->18.8MB signature). WORSE.
//   Remaining 3.33us/step is intrinsic cross-CU latency (drain ->
//   publish -> observe -> bulk -> stage -> compute); bandwidth,
//   word-contention, poll count, relay hops each falsified individually
//   (R20/R24/R25/R27). Per-slice pipelined consume rejected: conflicts
//   with the coalesced-bulk + LDS-broadcast structure R23 proved
//   essential (1766->3230 when broken).
//   Proven-mechanism ledger (for future sessions):
//   - Cross-CU signal writes MUST be atomic RMWs (execute at L2);
//     plain/sc0 stores linger in the store buffer (R16 hang, R17/R18).
//   - Polls: RMW add-0 sc0 (R21). Data: plain write-through stores +
//     pipelined sc0 loads under the XCC-probe same-XCD verdict (R17+).
//   - Transposed MFMA (operand swap) => packed 8B h-stores, absmax 0.
//   - Producer-side publish (per-wave vmcnt drain + LDS pcnt) replaces
//     B4; parity-kept Rs + B3 ordering unchanged.
// ws layout (~33.82 MiB):
//   X      fp16 [T][B][E]        @ 0          (33,554,432 B)
//   Hq     fp16 [2][8][16][512]  @ 33,554,432 (262,144 B)
//   FlagA  u32  [2][8][16]       @ 33,816,576 (1,024 B)  atomic/L2 channel
//   FlagB  u32  [2][8][16]       @ 33,817,600 (1,024 B)  agent/LLC channel
//   XccTab u32  [128]            @ 33,818,624 (512 B)
//   (FlagA..XccTab = 2,560 B contiguous, memset 0 each launch)

#define B_ 128
#define T_ 512
#define E_ 256
#define U_ 512
#define NWG_ 128
#define HROW_ 516   // Hs row stride (halves)

typedef __attribute__((ext_vector_type(4))) _Float16 half4;
typedef __attribute__((ext_vector_type(4))) float floatx4;
typedef unsigned long long u64t;
typedef unsigned int u32t;

#define MFMA16 __builtin_amdgcn_mfma_f32_16x16x16f16

__device__ __forceinline__ float sigmf(float x) { return 1.0f / (1.0f + __expf(-x)); }
__device__ __forceinline__ float tanh_f(float x) { return 2.0f / (1.0f + __expf(-2.0f * x)) - 1.0f; }

// X[t][b][e] = (fp16) emb[sentence[b][t]][e]; one thread = 8 elements.
__global__ void prep_x_kernel(const int* __restrict__ sent,
                              const float* __restrict__ emb,
                              _Float16* __restrict__ X) {
  int gid = blockIdx.x * blockDim.x + threadIdx.x;  // 2,097,152 total
  int e8 = gid & 31;
  int row = gid >> 5;         // row = t*128 + b
  int b = row & 127;
  int t = row >> 7;
  int word = sent[b * T_ + t];
  const float* src = emb + (size_t)word * E_ + e8 * 8;
  float4 v0 = *(const float4*)(src);
  float4 v1 = *(const float4*)(src + 4);
  _Float16 o[8] = {(_Float16)v0.x, (_Float16)v0.y, (_Float16)v0.z, (_Float16)v0.w,
                   (_Float16)v1.x, (_Float16)v1.y, (_Float16)v1.z, (_Float16)v1.w};
  _Float16* dst = X + (size_t)row * E_ + e8 * 8;
  *(half4*)dst = *(half4*)o;
  *(half4*)(dst + 4) = *(half4*)(o + 4);
}

__global__ __launch_bounds__(512, 1) void lstm_kernel(
    const _Float16* __restrict__ X,
    const float* __restrict__ Wx, const float* __restrict__ Wh,
    const float* __restrict__ bias,
    _Float16* __restrict__ Hq, u32t* FlagA, u32t* FlagB, u32t* XccTab) {
  // LDS: Hs [16][HROW_] fp16 (16,512) | Rs float[4][512] (8,192) |
  // xl u32[128] (512) | go u32 | pcnt u32 = 25,224 used; padded to 96 KB.
  __shared__ __align__(16) char smem[98304];
  _Float16* Hs = (_Float16*)smem;
  float* Rs = (float*)(smem + 16512);
  u32t* xl = (u32t*)(smem + 24704);
  volatile u32t* goP = (volatile u32t*)(smem + 25216);
  u32t* pcntP = (u32t*)(smem + 25220);

  const int bid = blockIdx.x;
  const int d = bid & 7;    // domain: rows d*16 .. d*16+15 (one XCD, verified)
  const int s = bid >> 3;   // unit slice: units s*32 .. s*32+31
  const int tid = threadIdx.x;
  const int lane = tid & 63;
  const int wave = tid >> 6;      // 8 waves
  const int p16 = lane & 15;
  const int quad = lane >> 4;
  const int sg = wave & 3;        // unit subgroup (8 units)
  const int kh = wave >> 2;       // 0: exchange + h[0,256) + epilogue
                                  // 1: x-GEMM + h[256,512)

  // ---- one-time XCD-mapping probe (gates the L2-local DATA path) ----
  // hwreg(HW_REG_XCC_ID=20, offset=0, size=32) -> imm = (31<<11)|20 = 63508
  if (tid == 0) {
    *goP = 0u;
    *pcntP = 0u;
    u32t myx = (u32t)__builtin_amdgcn_s_getreg(63508) & 0xFFu;
    __hip_atomic_store(XccTab + bid, 0x5A5A0000u | myx, __ATOMIC_RELAXED,
                       __HIP_MEMORY_SCOPE_AGENT);
  }
  if (wave == 0) {
    u32t v0, v1;
    for (;;) {
      v0 = __hip_atomic_load(XccTab + lane, __ATOMIC_RELAXED,
                             __HIP_MEMORY_SCOPE_AGENT);
      v1 = __hip_atomic_load(XccTab + 64 + lane, __ATOMIC_RELAXED,
                             __HIP_MEMORY_SCOPE_AGENT);
      if (__all(((v0 >> 16) == 0x5A5Au) & ((v1 >> 16) == 0x5A5Au))) break;
      __builtin_amdgcn_s_sleep(8);
    }
    xl[lane] = v0;
    xl[lane + 64] = v1;
  }
  __syncthreads();
  int fastv;
  {
    const u32t ref = xl[d];
    bool dom = true;
    for (int j = 1; j < 16; ++j) dom = dom && (xl[d + 8 * j] == ref);
    bool sane = false;  // getreg sanity: a constant-reading getreg -> slow
    const u32t z0 = xl[0];
    for (int e = 1; e < 128; ++e) sane = sane || (xl[e] != z0);
    fastv = (dom && sane) ? 1 : 0;
  }
  const bool fastp = (bool)__builtin_amdgcn_readfirstlane(fastv);

  // ---- one-time: gather this wave's B-fragments into VGPRs ----
  // (With operands swapped, this data is the A'-fragment
  //  A'[m=lane&15][k=quad*4+j] = W[gk][C(m)].)
  const int C0 = ((p16 >> 3) & 1) * 512 + s * 32 + sg * 8 + (p16 & 7);  // i/f
  const int C1 = C0 + 1024;                                             // g/o
  half4 b0r[32], b1r[32];
  if (kh == 0) {
#pragma unroll
    for (int i = 0; i < 16; ++i) {
      int kb = 16 + i;
#pragma unroll
      for (int j = 0; j < 4; ++j) {
        int gk = kb * 16 + quad * 4 + j;
        b0r[i][j] = (_Float16)Wh[(size_t)(gk - E_) * 2048 + C0];
        b1r[i][j] = (_Float16)Wh[(size_t)(gk - E_) * 2048 + C1];
      }
    }
  } else {
#pragma unroll
    for (int i = 0; i < 32; ++i) {
      int kb = (i < 16) ? i : (16 + i);
#pragma unroll
      for (int j = 0; j < 4; ++j) {
        int gk = kb * 16 + quad * 4 + j;
        float w0 = (gk < E_) ? Wx[(size_t)gk * 2048 + C0]
                             : Wh[(size_t)(gk - E_) * 2048 + C0];
        float w1 = (gk < E_) ? Wx[(size_t)gk * 2048 + C1]
                             : Wh[(size_t)(gk - E_) * 2048 + C1];
        b0r[i][j] = (_Float16)w0;
        b1r[i][j] = (_Float16)w1;
      }
    }
  }

  // ---- transposed-epilogue constants (kh0) ----
  // lane (p16=batch row, quad): units u0..u0+3, u0 = s*32+sg*8+(quad&1)*4.
  // quad0/1 lanes own i(acc0)/g(acc1); quad2/3 hold f/o for the same units.
  const int u0 = s * 32 + sg * 8 + (quad & 1) * 4;
  const floatx4 bi = *(const floatx4*)(bias + u0);          // i
  const floatx4 bf = *(const floatx4*)(bias + 512 + u0);    // f
  const floatx4 bg = *(const floatx4*)(bias + 1024 + u0);   // g
  const floatx4 bo = *(const floatx4*)(bias + 1536 + u0);   // o

  float cst[4] = {0.f, 0.f, 0.f, 0.f};  // c-state (kh0, quad<2 lanes)

  const int brow = d * 16 + p16;   // x/h fragment batch row
  const int ko = quad * 4;

  for (int t = 0; t < T_; ++t) {
    const int pin = t & 1, pout = pin ^ 1;

    floatx4 acc0 = {0.f, 0.f, 0.f, 0.f};
    floatx4 acc1 = {0.f, 0.f, 0.f, 0.f};

    if (kh == 1) {
      // ---- x-GEMM (kh1 only): 16 K16-blocks, operands swapped ----
      const _Float16* xr = X + ((size_t)t * B_ + brow) * E_ + ko;
#pragma unroll
      for (int i = 0; i < 16; ++i) {
        half4 a = *(const half4*)(xr + i * 16);
        acc0 = MFMA16(b0r[i], a, acc0, 0, 0, 0);
        acc1 = MFMA16(b1r[i], a, acc1, 0, 0, 0);
      }
    } else if (t > 0) {
      // ---- exchange (kh0 only): gate + bulk + stage, overlaps kh1's x ----
      const u32t tgt = (u32t)t;
      if (wave == 0) {
        // wave 0 is the sole poller (16 lanes, 16 distinct flag words).
        u32t v;
        if (fastp) {
          u32t* fa = FlagA + (size_t)(pin * 8 + d) * 16;
          const u32t* fb = FlagB + (size_t)(pin * 8 + d) * 16;
          int budget = 512;   // R21-proven RMW channel; fallback = hang guard
          for (;;) {
            if (budget > 0) {
              u32t old = tgt;
              if (lane < 16) {
                u32t* ap = fa + lane;
                asm volatile(
                    "global_atomic_add %0, %1, %2, off sc0\n\t"
                    "s_waitcnt vmcnt(0)"
                    : "=&v"(old) : "v"(ap), "v"(0u) : "memory");
              }
              v = old;
            } else {
              v = (lane < 16)
                      ? __hip_atomic_load(fb + lane, __ATOMIC_RELAXED,
                                          __HIP_MEMORY_SCOPE_AGENT)
                      : tgt;
            }
            if (__all(v == tgt)) break;
            --budget;
            if (budget < 500) __builtin_amdgcn_s_sleep(1);
          }
        } else {
          const u32t* fb = FlagB + (size_t)(pin * 8 + d) * 16;
          for (;;) {
            v = (lane < 16)
                    ? __hip_atomic_load(fb + lane, __ATOMIC_RELAXED,
                                        __HIP_MEMORY_SCOPE_AGENT)
                    : tgt;
            if (__all(v == tgt)) break;
            __builtin_amdgcn_s_sleep(1);
          }
        }
        if (lane == 0) *goP = tgt;   // LDS release for waves 1-3
      } else {
        // waves 1-3: LDS gate (wave0 wrote go=t after data-safe flag).
        u32t g;
        do { g = *goP; } while (g < tgt);
      }

      // bulk: 4 rows/wave (rows wave*4 .. wave*4+3), 8 chunks of 512B
      const _Float16* hq = Hq + ((size_t)(pin * 8 + d) * 16 + wave * 4) * 512;
      u64t hv[8];
      if (fastp) {
        // ONE asm block: 8 pipelined sc0 loads (imm offsets), one vmcnt(0).
        const u64t* hqb = (const u64t*)hq + lane;
        u64t h0, h1, h2, h3, h4, h5, h6, h7;
        asm volatile(
            "global_load_dwordx2 %0, %8, off sc0\n\t"
            "global_load_dwordx2 %1, %8, off offset:512 sc0\n\t"
            "global_load_dwordx2 %2, %8, off offset:1024 sc0\n\t"
            "global_load_dwordx2 %3, %8, off offset:1536 sc0\n\t"
            "global_load_dwordx2 %4, %8, off offset:2048 sc0\n\t"
            "global_load_dwordx2 %5, %8, off offset:2560 sc0\n\t"
            "global_load_dwordx2 %6, %8, off offset:3072 sc0\n\t"
            "global_load_dwordx2 %7, %8, off offset:3584 sc0\n\t"
            "s_waitcnt vmcnt(0)"
            : "=&v"(h0), "=&v"(h1), "=&v"(h2), "=&v"(h3),
              "=&v"(h4), "=&v"(h5), "=&v"(h6), "=&v"(h7)
            : "v"(hqb)
            : "memory");
        hv[0] = h0; hv[1] = h1; hv[2] = h2; hv[3] = h3;
        hv[4] = h4; hv[5] = h5; hv[6] = h6; hv[7] = h7;
      } else {
#pragma unroll
        for (int j = 0; j < 8; ++j) {
          size_t idx = (size_t)(j >> 1) * 128 + (j & 1) * 64 + lane;
          hv[j] = __hip_atomic_load((const u64t*)hq + idx, __ATOMIC_RELAXED,
                                    __HIP_MEMORY_SCOPE_AGENT);
        }
      }
#pragma unroll
      for (int j = 0; j < 8; ++j) {
        int r = wave * 4 + (j >> 1), half = j & 1;
        *(u64t*)(Hs + r * HROW_ + half * 256 + lane * 4) = hv[j];
      }
    }
    __syncthreads();  // B2: slab ready + x partial-accs in flight

    if (t > 0) {
      // ---- h-GEMM from slab (operands swapped; reads unchanged) ----
#pragma unroll
      for (int i = 0; i < 16; ++i) {
        int hk = kh * 16 + i;
        half4 a = *(const half4*)(Hs + p16 * HROW_ + hk * 16 + ko);
        const int wi = (kh == 0) ? i : (16 + i);
        acc0 = MFMA16(b0r[wi], a, acc0, 0, 0, 0);
        acc1 = MFMA16(b1r[wi], a, acc1, 0, 0, 0);
      }
    }

    // ---- kh1 partials -> Rs (same transposed layout both kh groups) ----
    if (kh == 1) {
      float* wb = Rs + sg * 512;
      *(floatx4*)(wb + lane * 4) = acc0;
      *(floatx4*)(wb + 256 + lane * 4) = acc1;
    }
    __syncthreads();  // B3: partials ready. kh1 then free-runs to t+1.

    // ---- epilogue (kh0): transposed — packed 8B h store per lane ----
    if (kh == 0) {
      const float* rb = Rs + sg * 512;
      floatx4 z0v = acc0 + *(const floatx4*)(rb + lane * 4);      // i | f
      floatx4 z1v = acc1 + *(const floatx4*)(rb + 256 + lane * 4); // g | o
      half4 hp4;
#pragma unroll
      for (int r = 0; r < 4; ++r) {
        float fraw = __shfl_xor(z0v[r], 32, 64);  // partner's f (quad<2 rx)
        float oraw = __shfl_xor(z1v[r], 32, 64);  // partner's o
        float iv = sigmf(z0v[r] + bi[r]);
        float gv = tanh_f(z1v[r] + bg[r]);
        float fv = sigmf(fraw + bf[r]);
        float ov = sigmf(oraw + bo[r]);
        float cn = fv * cst[r] + iv * gv;
        cst[r] = cn;
        hp4[r] = (_Float16)(ov * tanh_f(cn));
      }
      if (quad < 2) {
        // h for units u0..u0+3 of batch row p16: ONE contiguous 8B store.
        u64t pk = __builtin_bit_cast(u64t, hp4);
        u64t* hp =
            (u64t*)(Hq + ((size_t)(pout * 8 + d) * 16 + p16) * 512 + u0);
        if (fastp) {
          *hp = pk;  // plain: L1 write-through -> dirty in local XCD-L2
        } else {
          __hip_atomic_store(hp, pk, __ATOMIC_RELAXED,
                             __HIP_MEMORY_SCOPE_AGENT);
        }
      }

      // ---- publish: per-wave drain + LDS counter (R22-proven) ----
      asm volatile("s_waitcnt vmcnt(0)" ::: "memory");
      __builtin_amdgcn_sched_barrier(0);
      if (lane == 0) {
        u32t old = atomicAdd(pcntP, 1u);
        if (old == (u32t)(4 * t + 3)) {
          size_t fo = (size_t)(pout * 8 + d) * 16 + s;
          if (fastp) {
            u32t* ap = FlagA + fo;
            u32t nv = (u32t)(t + 1);
            asm volatile("global_atomic_swap %0, %1, off"
                         :: "v"(ap), "v"(nv) : "memory");
          }
          __hip_atomic_store(FlagB + fo, (u32t)(t + 1), __ATOMIC_RELAXED,
                             __HIP_MEMORY_SCOPE_AGENT);  // progress channel
        }
      }
    }
  }
}

// MLP head: one block per batch row. h(512)->relu 128->relu 64->sigmoid 1.
// T=512 even -> final h in Hq parity 0. Kernel boundary orders prior stores
// (end-of-dispatch agent release writes back dirty L2 lines).
__global__ void head_kernel(const _Float16* __restrict__ Hq,
                            const float* __restrict__ W1, const float* __restrict__ b1,
                            const float* __restrict__ W2, const float* __restrict__ b2,
                            const float* __restrict__ W3, const float* __restrict__ b3,
                            float* __restrict__ out) {
  __shared__ float hs[512];
  __shared__ float h1[128];
  __shared__ float h2[64];
  int row = blockIdx.x;
  int tid = threadIdx.x;  // 128 threads
  int dd = row >> 4, rr = row & 15;
  const _Float16* hrow = Hq + ((size_t)dd * 16 + rr) * 512;
  for (int k = tid; k < 512; k += 128) hs[k] = (float)hrow[k];
  __syncthreads();
  float a = b1[tid];
  for (int k = 0; k < 512; ++k) a += hs[k] * W1[k * 128 + tid];
  h1[tid] = fmaxf(a, 0.0f);
  __syncthreads();
  if (tid < 64) {
    float a2 = b2[tid];
    for (int k = 0; k < 128; ++k) a2 += h1[k] * W2[k * 64 + tid];
    h2[tid] = fmaxf(a2, 0.0f);
  }
  __syncthreads();
  if (tid == 0) {
    float a3 = b3[0];
    for (int k = 0; k < 64; ++k) a3 += h2[k] * W3[k];
    out[row] = 1.0f / (1.0f + __expf(-a3));
  }
}

extern "C" void kernel_launch(void* const* d_in, const int* in_sizes, int n_in,
                              void* d_out, int out_size, void* d_ws, size_t ws_size,
                              hipStream_t stream) {
  const int* sent = (const int*)d_in[0];
  const float* emb = (const float*)d_in[1];
  const float* Wx = (const float*)d_in[2];
  const float* Wh = (const float*)d_in[3];
  const float* b = (const float*)d_in[4];
  const float* W1 = (const float*)d_in[5];
  const float* b1 = (const float*)d_in[6];
  const float* W2 = (const float*)d_in[7];
  const float* b2 = (const float*)d_in[8];
  const float* W3 = (const float*)d_in[9];
  const float* b3 = (const float*)d_in[10];
  float* out = (float*)d_out;

  char* ws = (char*)d_ws;
  _Float16* X = (_Float16*)(ws);
  _Float16* Hq = (_Float16*)(ws + (size_t)33554432);
  u32t* FlagA = (u32t*)(ws + (size_t)33554432 + 262144);
  u32t* FlagB = (u32t*)(ws + (size_t)33554432 + 263168);
  u32t* XccTab = (u32t*)(ws + (size_t)33554432 + 264192);

  // Zero FlagA+FlagB+XccTab (contiguous 2,560 B) every launch:
  // removes the first-launch garbage hazard; 0 never matches t in [1,512].
  hipMemsetAsync(FlagA, 0, 2560, stream);
  prep_x_kernel<<<8192, 256, 0, stream>>>(sent, emb, X);
  lstm_kernel<<<NWG_, 512, 0, stream>>>(X, Wx, Wh, b, Hq, FlagA, FlagB, XccTab);
  head_kernel<<<128, 128, 0, stream>>>(Hq, W1, b1, W2, b2, W3, b3, out);
}